// Round 2
// baseline (36.727 us; speedup 1.0000x reference)
//
#include <hip/hip_runtime.h>

#define DDIM   128
#define SCHUNK 8          // samples per chunk/block
#define NROWS  (3 * SCHUNK)
#define XPAD   (DDIM + 4) // pad row stride (528B) to de-alias LDS banks

// ---------------- Kernel A: bucket samples by relation ----------------
// ws int layout: [0]=nchunks | [64..64+B) bucket | then chrel / chstart / chcnt (maxch each)
__global__ __launch_bounds__(256) void bucket_kernel(
    const int* __restrict__ r, int B, int maxch, int* __restrict__ ws)
{
    const int t = threadIdx.x;
    __shared__ int cnt_s[256];
    __shared__ int scan_s[256];
    __shared__ int off_s[256];
    __shared__ int cur_s[256];

    cnt_s[t] = 0;
    __syncthreads();
    for (int i = t; i < B; i += 256) atomicAdd(&cnt_s[r[i]], 1);
    __syncthreads();

    // inclusive scan of counts
    int my = cnt_s[t];
    scan_s[t] = my;
    __syncthreads();
    for (int s = 1; s < 256; s <<= 1) {
        int add = (t >= s) ? scan_s[t - s] : 0;
        __syncthreads();
        scan_s[t] += add;
        __syncthreads();
    }
    off_s[t] = scan_s[t] - my;           // exclusive offset per relation
    __syncthreads();

    // scan of per-relation chunk counts
    int ck = (my + SCHUNK - 1) / SCHUNK;
    scan_s[t] = ck;
    __syncthreads();
    for (int s = 1; s < 256; s <<= 1) {
        int add = (t >= s) ? scan_s[t - s] : 0;
        __syncthreads();
        scan_s[t] += add;
        __syncthreads();
    }
    int chbase = scan_s[t] - ck;
    if (t == 255) ws[0] = scan_s[255];   // total chunks

    int* bucket  = ws + 64;
    int* chrel   = bucket + B;
    int* chstart = chrel + maxch;
    int* chcnt   = chstart + maxch;

    for (int k = 0; k < ck; ++k) {
        chrel[chbase + k]   = t;
        chstart[chbase + k] = off_s[t] + k * SCHUNK;
        chcnt[chbase + k]   = min(SCHUNK, my - k * SCHUNK);
    }

    cur_s[t] = off_s[t];
    __syncthreads();
    for (int i = t; i < B; i += 256) {
        int p = atomicAdd(&cur_s[r[i]], 1);
        bucket[p] = i;
    }
}

// ---------------- Kernel B: per-(relation,chunk) blocked GEMV ----------------
__global__ __launch_bounds__(256) void transr_main(
    const int* __restrict__ h, const int* __restrict__ pos_t, const int* __restrict__ neg_t,
    const float* __restrict__ ent, const float* __restrict__ rel,
    const float* __restrict__ M, float* __restrict__ out,
    const int* __restrict__ ws, int B, int maxch)
{
    const int nch = ws[0];
    const int bid = blockIdx.x;
    if (bid >= nch) return;

    const int* bucket  = ws + 64;
    const int* chrel   = bucket + B;
    const int* chstart = chrel + maxch;
    const int* chcnt   = chstart + maxch;

    const int t  = threadIdx.x;
    const int tx = t & 31;       // column group: e = tx*4 .. tx*4+3
    const int ty = t >> 5;       // sample within chunk (0..7)

    const int rb    = chrel[bid];
    const int start = chstart[bid];
    const int cnt   = chcnt[bid];

    __shared__ int   ssid[SCHUNK], sidh[SCHUNK], sidp[SCHUNK], sidn[SCHUNK];
    __shared__ float xs[NROWS][XPAD];

    if (t < SCHUNK) {
        int j = (t < cnt) ? t : (cnt - 1);   // pad with last valid sample
        int i = bucket[start + j];
        ssid[t] = i;
        sidh[t] = h[i];
        sidp[t] = pos_t[i];
        sidn[t] = neg_t[i];
    }
    __syncthreads();

    // stage 24 rows x 128 floats, float4-coalesced: 768 float4 / 256 thr = 3 iters
    for (int lin = t; lin < NROWS * (DDIM / 4); lin += 256) {
        int row = lin >> 5;          // /32
        int c4  = lin & 31;
        int j   = row / 3;
        int v   = row - 3 * j;
        int eid = (v == 0) ? sidh[j] : (v == 1) ? sidp[j] : sidn[j];
        float4 x = *(const float4*)(ent + (size_t)eid * DDIM + c4 * 4);
        *(float4*)(&xs[row][c4 * 4]) = x;
    }
    __syncthreads();

    const float* __restrict__ W = M + (size_t)rb * (DDIM * DDIM);
    const float* xr0 = &xs[ty * 3 + 0][0];
    const float* xr1 = &xs[ty * 3 + 1][0];
    const float* xr2 = &xs[ty * 3 + 2][0];

    float acc[3][4] = {};

#define STEP(cmp, wv)                                   \
    acc[0][0] = fmaf(x0.cmp, wv.x, acc[0][0]);          \
    acc[0][1] = fmaf(x0.cmp, wv.y, acc[0][1]);          \
    acc[0][2] = fmaf(x0.cmp, wv.z, acc[0][2]);          \
    acc[0][3] = fmaf(x0.cmp, wv.w, acc[0][3]);          \
    acc[1][0] = fmaf(x1.cmp, wv.x, acc[1][0]);          \
    acc[1][1] = fmaf(x1.cmp, wv.y, acc[1][1]);          \
    acc[1][2] = fmaf(x1.cmp, wv.z, acc[1][2]);          \
    acc[1][3] = fmaf(x1.cmp, wv.w, acc[1][3]);          \
    acc[2][0] = fmaf(x2.cmp, wv.x, acc[2][0]);          \
    acc[2][1] = fmaf(x2.cmp, wv.y, acc[2][1]);          \
    acc[2][2] = fmaf(x2.cmp, wv.z, acc[2][2]);          \
    acc[2][3] = fmaf(x2.cmp, wv.w, acc[2][3]);

#pragma unroll 4
    for (int d = 0; d < DDIM; d += 4) {
        float4 x0 = *(const float4*)(xr0 + d);
        float4 x1 = *(const float4*)(xr1 + d);
        float4 x2 = *(const float4*)(xr2 + d);
        float4 w0 = *(const float4*)(W + (size_t)(d + 0) * DDIM + tx * 4);
        float4 w1 = *(const float4*)(W + (size_t)(d + 1) * DDIM + tx * 4);
        float4 w2 = *(const float4*)(W + (size_t)(d + 2) * DDIM + tx * 4);
        float4 w3 = *(const float4*)(W + (size_t)(d + 3) * DDIM + tx * 4);
        STEP(x, w0)
        STEP(y, w1)
        STEP(z, w2)
        STEP(w, w3)
    }
#undef STEP

    if (ty < cnt) {
        size_t s = (size_t)ssid[ty];
        *(float4*)(out + s * DDIM + tx * 4) =
            make_float4(acc[0][0], acc[0][1], acc[0][2], acc[0][3]);                 // trans_h
        *(float4*)(out + (size_t)2 * B * DDIM + s * DDIM + tx * 4) =
            make_float4(acc[1][0], acc[1][1], acc[1][2], acc[1][3]);                 // trans_pos
        *(float4*)(out + (size_t)3 * B * DDIM + s * DDIM + tx * 4) =
            make_float4(acc[2][0], acc[2][1], acc[2][2], acc[2][3]);                 // trans_neg
    }

    // r_e gather (output slot 1)
    for (int lin = t; lin < cnt * DDIM; lin += 256) {
        int j = lin >> 7, col = lin & 127;
        out[(size_t)B * DDIM + (size_t)ssid[j] * DDIM + col] = rel[(size_t)rb * DDIM + col];
    }
}

extern "C" void kernel_launch(void* const* d_in, const int* in_sizes, int n_in,
                              void* d_out, int out_size, void* d_ws, size_t ws_size,
                              hipStream_t stream) {
    const int*   h     = (const int*)d_in[0];
    const int*   r     = (const int*)d_in[1];
    const int*   pos_t = (const int*)d_in[2];
    const int*   neg_t = (const int*)d_in[3];
    const float* ent   = (const float*)d_in[4];
    const float* rel   = (const float*)d_in[5];
    const float* M     = (const float*)d_in[6];
    float*       out   = (float*)d_out;
    int*         ws    = (int*)d_ws;

    const int B = in_sizes[0];
    const int maxch = B / SCHUNK + 256 + 1;   // upper bound on chunk count (R<=256)

    bucket_kernel<<<dim3(1), dim3(256), 0, stream>>>(r, B, maxch, ws);
    transr_main<<<dim3(maxch), dim3(256), 0, stream>>>(
        h, pos_t, neg_t, ent, rel, M, out, ws, B, maxch);
}